// Round 11
// baseline (4353.646 us; speedup 1.0000x reference)
//
#include <hip/hip_runtime.h>
#include <hip/hip_bf16.h>

// LSTM B=64 L=512 H=1024 x2, persistent kernel v11.
// v11 = v8 (best: 3.16ms) + ONE change: double-buffered planes (parity t&1)
// -> per-step B3 barrier deleted. v8's conflict-free pointwise mapping kept
// (v9's remap caused 2.1e8 LDS conflicts; v10's sentinel/bypass loads killed
// the L2-shared cached broadcast -- both reverted).
// Race audit: pointwise(t) reads planes[pb]; next writes hit planes[pb^1];
// the following planes[pb] write (t+2) is fenced by B2(t+1), which pw waves
// reach only after pointwise(t). Ring fallback keeps a conditional B3.

#define B64  64
#define SEQ  512
#define HID  1024
#define KTOT 2048
#define NG   4096
#define DPB  16
#define SLOT32 32768           // shorts per (t, rhalf) frag slot = 128kg*32r*8
#define NSLOT (SEQ+1)

typedef __attribute__((ext_vector_type(8)))  short short8;
typedef __attribute__((ext_vector_type(16))) float f32x16;

__device__ inline short bfo(float v){
  __hip_bfloat16 h = __float2bfloat16(v);
  short s; __builtin_memcpy(&s, &h, 2); return s;
}
__device__ inline unsigned packbf2(float a, float b){
  return (unsigned)(unsigned short)bfo(a) | ((unsigned)(unsigned short)bfo(b) << 16);
}
__device__ inline short8 cvt8(float4 a, float4 b){
  short8 r;
  r[0]=bfo(a.x); r[1]=bfo(a.y); r[2]=bfo(a.z); r[3]=bfo(a.w);
  r[4]=bfo(b.x); r[5]=bfo(b.y); r[6]=bfo(b.z); r[7]=bfo(b.w);
  return r;
}
__device__ inline float frcp(float x){ float r; asm("v_rcp_f32 %0, %1" : "=v"(r) : "v"(x)); return r; }
__device__ inline float sigf(float v){ return frcp(1.f + __expf(-v)); }
__device__ inline float tanhf2(float v){
  float a = fabsf(v);
  float e = __expf(-2.f*a);
  float r = (1.f - e) * frcp(1.f + e);
  return v < 0.f ? -r : r;
}
__device__ inline f32x16 MFMA(short8 a, short8 b, f32x16 c){
  return __builtin_amdgcn_mfma_f32_32x32x16_bf16(a, b, c, 0, 0, 0);
}
__device__ inline void stu(short* p, unsigned v){
  __hip_atomic_store((unsigned*)p, v, __ATOMIC_RELAXED, __HIP_MEMORY_SCOPE_AGENT);
}
__device__ inline void st8f(float* p, float a, float b){
  unsigned ua, ub; __builtin_memcpy(&ua, &a, 4); __builtin_memcpy(&ub, &b, 4);
  unsigned long long v = (unsigned long long)ua | ((unsigned long long)ub << 32);
  __hip_atomic_store((unsigned long long*)p, v, __ATOMIC_RELAXED, __HIP_MEMORY_SCOPE_AGENT);
}
__device__ inline unsigned pollld(const unsigned* p){
  return __hip_atomic_load(p, __ATOMIC_RELAXED, __HIP_MEMORY_SCOPE_AGENT);
}
__device__ inline short8 ldh8(const short* p){
  unsigned long long a = __hip_atomic_load((const unsigned long long*)p,
                          __ATOMIC_RELAXED, __HIP_MEMORY_SCOPE_AGENT);
  unsigned long long b = __hip_atomic_load((const unsigned long long*)(p+4),
                          __ATOMIC_RELAXED, __HIP_MEMORY_SCOPE_AGENT);
  short8 r;
  __builtin_memcpy(&r, &a, 8);
  __builtin_memcpy(((char*)&r)+8, &b, 8);
  return r;
}

// pipelined 2-outstanding poll: lane checks win[lane] >= e, all 64 lanes.
__device__ inline void wait_ge(const unsigned* win, unsigned e, int lane){
  const unsigned* fp = win + lane;
  unsigned f0, f1;
  asm volatile(
    "global_load_dword %[f0], %[ad], off sc0 sc1\n\t"
    "Lp%=:\n\t"
    "global_load_dword %[f1], %[ad], off sc0 sc1\n\t"
    "s_waitcnt vmcnt(1)\n\t"
    "v_cmp_ge_u32 vcc, %[f0], %[e]\n\t"
    "s_cmp_eq_u64 vcc, -1\n\t"
    "s_cbranch_scc1 Ld%=\n\t"
    "global_load_dword %[f0], %[ad], off sc0 sc1\n\t"
    "s_waitcnt vmcnt(1)\n\t"
    "v_cmp_ge_u32 vcc, %[f1], %[e]\n\t"
    "s_cmp_eq_u64 vcc, -1\n\t"
    "s_cbranch_scc0 Lp%=\n\t"
    "Ld%=:\n\t"
    "s_waitcnt vmcnt(0)\n\t"
    : [f0]"=&v"(f0), [f1]"=&v"(f1)
    : [ad]"v"(fp), [e]"v"(e)
    : "vcc", "scc", "memory");
}

// ring-fallback: all 256 per-wave flags of a domain >= e
__device__ inline void waitflags_all256(const unsigned* f, unsigned e, int lane){
  for(;;){
    unsigned m0 = pollld(f + lane),       m1 = pollld(f + 64 + lane);
    unsigned m2 = pollld(f + 128 + lane), m3 = pollld(f + 192 + lane);
    if (__all((m0>=e) && (m1>=e) && (m2>=e) && (m3>=e))) break;
  }
  asm volatile("" ::: "memory");
}

// A-panel GEMM: K=256 eighth, 16 kg-pairs, dual accumulator chains.
__device__ inline void gemmA_core(const short* __restrict__ slot, int lane, int kgbase,
                                  const short8 (&bf)[2][16], f32x16& A0, f32x16& A1)
{
  const int row = lane & 31, ksel = lane >> 5;
  f32x16 x0, x1, y0, y1;
#pragma unroll
  for (int i = 0; i < 16; ++i){ x0[i]=0.f; x1[i]=0.f; y0[i]=0.f; y1[i]=0.f; }
#pragma unroll
  for (int s = 0; s < 16; s += 2){
    const short8 a  = *(const short8*)(slot + ((size_t)(kgbase + s*2     + ksel)*32 + row)*8);
    const short8 a2 = *(const short8*)(slot + ((size_t)(kgbase + (s+1)*2 + ksel)*32 + row)*8);
    x0 = MFMA(a,  bf[0][s],   x0);
    x1 = MFMA(a,  bf[1][s],   x1);
    y0 = MFMA(a2, bf[0][s+1], y0);
    y1 = MFMA(a2, bf[1][s+1], y1);
  }
  A0 = x0 + y0;
  A1 = x1 + y1;
}
__device__ inline void gemmA_wait(const short* __restrict__ slot,
                                  const unsigned* __restrict__ win, unsigned e,
                                  int lane, int kgbase,
                                  const short8 (&bf)[2][16], f32x16& A0, f32x16& A1)
{
  wait_ge(win, e, lane);
  gemmA_core(slot, lane, kgbase, bf, A0, A1);
}
__device__ inline void gemmA_bp(const short* __restrict__ slot, int lane, int kgbase,
                                const short8 (&bf)[2][16], f32x16& A0, f32x16& A1)
{
  const int row = lane & 31, ksel = lane >> 5;
  f32x16 x0, x1;
#pragma unroll
  for (int i = 0; i < 16; ++i){ x0[i]=0.f; x1[i]=0.f; }
#pragma unroll
  for (int s = 0; s < 16; ++s){
    const short8 a = ldh8(slot + ((size_t)(kgbase + s*2 + ksel)*32 + row)*8);
    x0 = MFMA(a, bf[0][s], x0);
    x1 = MFMA(a, bf[1][s], x1);
  }
  A0 = x0; A1 = x1;
}

// ---------------- prologue kernels ----------------

__global__ void lstm_prep(const float* __restrict__ bi, const float* __restrict__ bh,
                          float* __restrict__ bsum, unsigned* __restrict__ flags)
{
  int i = blockIdx.x*256 + threadIdx.x;
  if (i < 1024) flags[i] = 0;            // 4 domains x 64 blk x 4 pw-waves
  if (i < 2*NG) bsum[i] = bi[i] + bh[i];
}

// W_i/W_h [2][1024][4096] f32 -> wT [2][4096][2048] bf16 (gate-col major, k inner)
__global__ void lstm_tr(const float* __restrict__ Wi, const float* __restrict__ Wh,
                        short* __restrict__ wT)
{
  __shared__ float tile[32][33];
  const int z = blockIdx.z, l = z >> 1, s = z & 1;
  const float* W = (s ? Wh : Wi) + (size_t)l*1024*4096;
  const int k0 = blockIdx.y*32, n0 = blockIdx.x*32;
  const int tx = threadIdx.x & 31, ty = threadIdx.x >> 5;
#pragma unroll
  for (int i = 0; i < 32; i += 8)
    tile[ty+i][tx] = W[(size_t)(k0+ty+i)*4096 + n0 + tx];
  __syncthreads();
#pragma unroll
  for (int i = 0; i < 32; i += 8)
    wT[((size_t)l*NG + n0+ty+i)*KTOT + s*1024 + k0 + tx] = bfo(tile[tx][ty+i]);
}

// x [64][512][1024] f32 -> xf [512][2 rh][128 kg][32 r][8] bf16
__global__ void lstm_xfrag(const float* __restrict__ x, short* __restrict__ xf)
{
  const int t = blockIdx.x;
  const int rh = blockIdx.y >> 4, kgb = blockIdx.y & 15;   // grid (512, 32)
  const int r = threadIdx.x >> 3, kq = threadIdx.x & 7;
  const int kg = kgb*8 + kq;
  const int grow = rh*32 + r;
  const float* p = x + ((size_t)grow*SEQ + t)*HID + kg*8;
  float4 a = *(const float4*)p, b = *(const float4*)(p + 4);
  *(short8*)(xf + ((size_t)t*2 + rh)*SLOT32 + ((size_t)kg*32 + r)*8) = cvt8(a, b);
}

// ---------------- main persistent kernel ----------------

__global__ void __launch_bounds__(512, 1)
lstm_main(const float* __restrict__ x,
          const float* __restrict__ h0in,
          const float* __restrict__ c0in,
          float* __restrict__ dout,
          const short* __restrict__ wT,
          const float* __restrict__ bsum,
          short* __restrict__ hseq0,
          short* __restrict__ h1seq,
          unsigned* __restrict__ flags,
          const short* __restrict__ xf,
          int use_xf, int use_seq1)
{
  const int blk  = blockIdx.x;          // 256 blocks
  const int l    = blk & 1;             // layer
  const int rh   = (blk >> 1) & 1;      // row half (rows rh*32..+32)
  const int lblk = blk >> 2;            // 0..63, owns dims [lblk*16,+16)
  const int dom  = blk & 3;             // sync domain = (rh,l)
  const int dom0 = 2*rh;                // layer-0 domain of same row half
  const int tid  = threadIdx.x;
  const int lane = tid & 63;
  const int w    = tid >> 6;            // K-eighth: w<4 = x-part, w>=4 = h-part
  const int c31  = lane & 31;

  __shared__ float planes[2][8][32][65];  // DOUBLE-buffered (parity t&1)
  __shared__ float cst[32][17];
  __shared__ float bsm[64];

  __builtin_amdgcn_fence(__ATOMIC_ACQUIRE, "agent");   // once: drop stale lines

  unsigned* dfl  = flags + dom*256;     // [64 blk][4 pw-wave] flags
  unsigned* dfl0 = flags + dom0*256;

  // pointwise mapping (waves 0-3): row = lane&31, dim pair dp = w*2 + (lane>>5)
  const int prow = lane & 31;
  const int pd0  = (w*2 + (lane>>5)) * 2;    // first of 2 dims (valid for w<4)

  // ---- init ----
  if (tid < 64) bsm[tid] = bsum[l*NG + (tid>>4)*HID + lblk*DPB + (tid&15)];
  if (w < 4){
    size_t o = ((size_t)l*B64 + rh*32 + prow)*HID + lblk*DPB + pd0;
    cst[prow][pd0]   = c0in[o];
    cst[prow][pd0+1] = c0in[o+1];
    const int kg = lblk*2 + (pd0>>3);
    short* hm1 = (l ? h1seq : hseq0) + (size_t)rh*SLOT32;   // slot 0 (both modes)
    stu(hm1 + ((size_t)kg*32 + prow)*8 + (pd0&7), packbf2(h0in[o], h0in[o+1]));
  }
  // persistent B fragments: 64 cols x 256 k = 128 VGPRs
  short8 bf[2][16];
  {
    const short* wl = wT + (size_t)l*NG*KTOT;
#pragma unroll
    for (int cI = 0; cI < 2; ++cI){
      const int c  = cI*32 + c31;
      const int gc = (c>>4)*HID + lblk*DPB + (c&15);
      const short* wp = wl + (size_t)gc*KTOT + w*256 + (lane>>5)*8;
#pragma unroll
      for (int s = 0; s < 16; ++s)
        bf[cI][s] = *(const short8*)(wp + s*16);
    }
  }
  __syncthreads();    // drains vmcnt: init write-through stores in LLC
  if (w < 4 && lane == 0)
    __hip_atomic_store(dfl + lblk*4 + w, 1u, __ATOMIC_RELAXED, __HIP_MEMORY_SCOPE_AGENT);

  float hf0 = 0.f, hf1 = 0.f;

  for (int t = 0; t < SEQ; ++t){
    const int pb = t & 1;
    f32x16 a0, a1;

    if (w < 4){
      // ---- x-part ----
      if (l == 0){
        if (use_xf){
          gemmA_core(xf + ((size_t)t*2 + rh)*SLOT32, lane, w*32, bf, a0, a1);
        } else {
          const int row = lane & 31, ksel = lane >> 5;
          const float* p = x + ((size_t)(rh*32 + row)*SEQ + t)*HID;
          f32x16 x0, x1;
#pragma unroll
          for (int i = 0; i < 16; ++i){ x0[i]=0.f; x1[i]=0.f; }
#pragma unroll
          for (int s = 0; s < 16; ++s){
            const int kg = w*32 + s*2 + ksel;
            short8 a = cvt8(*(const float4*)(p + kg*8), *(const float4*)(p + kg*8 + 4));
            x0 = MFMA(a, bf[0][s], x0);
            x1 = MFMA(a, bf[1][s], x1);
          }
          a0 = x0; a1 = x1;
        }
      } else {
        // layer-1 input = h0(t): hseq0 slot t+1; window = 16 l0 blocks x 4 waves
        gemmA_wait(hseq0 + ((size_t)(t+1)*2 + rh)*SLOT32,
                   dfl0 + w*64, (unsigned)t + 2u,
                   lane, w*32, bf, a0, a1);
      }
    } else {
      // ---- h-part: own layer h(t-1) ----
      if (l == 0){
        gemmA_wait(hseq0 + ((size_t)t*2 + rh)*SLOT32,
                   dfl + (w-4)*64, (unsigned)t + 1u,
                   lane, (w-4)*32, bf, a0, a1);
      } else if (use_seq1){
        gemmA_wait(h1seq + ((size_t)t*2 + rh)*SLOT32,
                   dfl + (w-4)*64, (unsigned)t + 1u,
                   lane, (w-4)*32, bf, a0, a1);
      } else {
        waitflags_all256(dfl, (unsigned)t + 1u, lane);
        gemmA_bp(h1seq + ((size_t)(t&1)*2 + rh)*SLOT32, lane, (w-4)*32, bf, a0, a1);
      }
    }

    // ---- each wave writes its OWN plane (parity pb) ----
#pragma unroll
    for (int r = 0; r < 16; ++r){
      const int rr = (r&3) + 8*(r>>2) + 4*(lane>>5);
      planes[pb][w][rr][c31]      = a0[r];
      planes[pb][w][rr][32 + c31] = a1[r];
    }
    __syncthreads();   // B2: all planes(pb) written; also fences pb-reuse (t+2)

    // ---- pointwise (waves 0-3, all 64 lanes; 2 dims x 1 row each) ----
    if (w < 4){
      float hn[2];
#pragma unroll
      for (int e = 0; e < 2; ++e){
        const int d = pd0 + e;
        float gv[4];
#pragma unroll
        for (int g = 0; g < 4; ++g){
          float s = bsm[g*16 + d];
#pragma unroll
          for (int p = 0; p < 8; ++p)
            s += planes[pb][p][prow][g*16 + d];
          gv[g] = s;
        }
        float cp = cst[prow][d];
        float cn = sigf(gv[1])*cp + sigf(gv[0])*tanhf2(gv[2]);
        float hv = sigf(gv[3])*tanhf2(cn);
        cst[prow][d] = cn;
        hn[e] = hv;
      }
      hf0 = hn[0]; hf1 = hn[1];
      const int kg = lblk*2 + (pd0>>3);
      short* so;
      if (l == 0)           so = hseq0 + ((size_t)(t+1)*2 + rh)*SLOT32;
      else if (use_seq1)    so = h1seq + ((size_t)(t+1)*2 + rh)*SLOT32;
      else                  so = h1seq + ((size_t)((t+1)&1)*2 + rh)*SLOT32;
      stu(so + ((size_t)kg*32 + prow)*8 + (pd0&7), packbf2(hn[0], hn[1]));
      asm volatile("s_waitcnt vmcnt(0)" ::: "memory");   // wave-local store ack
      if (lane == 0)
        __hip_atomic_store(dfl + lblk*4 + w, (unsigned)t + 2u,
                           __ATOMIC_RELAXED, __HIP_MEMORY_SCOPE_AGENT);
      // off critical path: layer-1 output write
      if (l == 1)
        st8f(dout + ((size_t)(rh*32 + prow)*SEQ + t)*HID + lblk*DPB + pd0, hn[0], hn[1]);
    }
    // NO B3 on the main path (double-buffered planes). Ring fallback keeps it
    // (stricter ordering for slot reuse); predicate is block-uniform.
    if (l == 1 && !use_seq1) __syncthreads();
  }

  // ---- epilogue: h_n / c_n ----
  if (w < 4){
    const int grow = rh*32 + prow;
    const size_t tb = (size_t)B64*SEQ*HID;
    size_t o = ((size_t)l*B64 + grow)*HID + lblk*DPB + pd0;
    st8f(dout + tb + o, hf0, hf1);
    st8f(dout + tb + (size_t)2*B64*HID + o, cst[prow][pd0], cst[prow][pd0+1]);
  }
}

// ---------------- host ----------------

extern "C" void kernel_launch(void* const* d_in, const int* in_sizes, int n_in,
                              void* d_out, int out_size, void* d_ws, size_t ws_size,
                              hipStream_t stream)
{
  const float* x  = (const float*)d_in[0];
  const float* Wi = (const float*)d_in[1];
  const float* bi = (const float*)d_in[2];
  const float* Wh = (const float*)d_in[3];
  const float* bh = (const float*)d_in[4];
  const float* h0 = (const float*)d_in[5];
  const float* c0 = (const float*)d_in[6];
  float* out = (float*)d_out;

  char* ws = (char*)d_ws;
  unsigned* flags = (unsigned*)ws;                     // 4 dom x 64 blk x 4 w
  float*    bsum  = (float*)(ws + 16384);              // 32 KB
  short*    wT    = (short*)(ws + 131072);             // 32 MB

  const size_t wT_bytes  = (size_t)2*NG*KTOT*2;        // 33,554,432
  const size_t seq_bytes = (size_t)NSLOT*2*SLOT32*2;   // 67.2 MB
  size_t off = 131072 + wT_bytes;

  short* hseq0 = (short*)(ws + off); off += seq_bytes; // required
  if (ws_size < off) return;

  int use_seq1 = 0;
  short* h1seq = (short*)(ws + off);
  if (ws_size >= off + seq_bytes){ use_seq1 = 1; off += seq_bytes; }
  else {
    if (ws_size < off + (size_t)2*2*SLOT32*2) return;  // 2-slot ring, 256 KB
    off += (size_t)2*2*SLOT32*2;
  }

  int use_xf = 0;
  short* xf = (short*)(ws + off);
  if (ws_size >= off + (size_t)SEQ*2*SLOT32*2) use_xf = 1;   // +67 MB

  lstm_prep<<<32, 256, 0, stream>>>(bi, bh, bsum, flags);
  lstm_tr<<<dim3(128, 32, 4), 256, 0, stream>>>(Wi, Wh, wT);
  if (use_xf) lstm_xfrag<<<dim3(SEQ, 32), 256, 0, stream>>>(x, xf);
  lstm_main<<<256, 512, 0, stream>>>(x, h0, c0, out, wT, bsum, hseq0, h1seq,
                                     flags, xf, use_xf, use_seq1);
}

// Round 12
// 4115.807 us; speedup vs baseline: 1.0578x; 1.0578x over previous
//
#include <hip/hip_runtime.h>
#include <hip/hip_bf16.h>

// LSTM B=64 L=512 H=1024 x2, persistent kernel v12.
// v12 = v8 (best measured: 3.16ms) + chunked opportunistic consumer wait.
// v8's wait_ge blocked on ALL 64 window flags before any MFMA; v12 polls once
// (same single wave-load), then processes ready 4-producer chunks in static
// order, re-polling only for missing chunks -> early fragments' MFMA overlaps
// straggler producers. Everything else byte-identical to v8.
// (v9 remap: -2.1e8 LDS conflicts, v10 sentinel: bypass-load bloat, v11 no-B3:
//  poll storm during store window -- all three reverted/dead.)

#define B64  64
#define SEQ  512
#define HID  1024
#define KTOT 2048
#define NG   4096
#define DPB  16
#define SLOT32 32768           // shorts per (t, rhalf) frag slot = 128kg*32r*8
#define NSLOT (SEQ+1)

typedef __attribute__((ext_vector_type(8)))  short short8;
typedef __attribute__((ext_vector_type(16))) float f32x16;

__device__ inline short bfo(float v){
  __hip_bfloat16 h = __float2bfloat16(v);
  short s; __builtin_memcpy(&s, &h, 2); return s;
}
__device__ inline unsigned packbf2(float a, float b){
  return (unsigned)(unsigned short)bfo(a) | ((unsigned)(unsigned short)bfo(b) << 16);
}
__device__ inline short8 cvt8(float4 a, float4 b){
  short8 r;
  r[0]=bfo(a.x); r[1]=bfo(a.y); r[2]=bfo(a.z); r[3]=bfo(a.w);
  r[4]=bfo(b.x); r[5]=bfo(b.y); r[6]=bfo(b.z); r[7]=bfo(b.w);
  return r;
}
__device__ inline float frcp(float x){ float r; asm("v_rcp_f32 %0, %1" : "=v"(r) : "v"(x)); return r; }
__device__ inline float sigf(float v){ return frcp(1.f + __expf(-v)); }
__device__ inline float tanhf2(float v){
  float a = fabsf(v);
  float e = __expf(-2.f*a);
  float r = (1.f - e) * frcp(1.f + e);
  return v < 0.f ? -r : r;
}
__device__ inline f32x16 MFMA(short8 a, short8 b, f32x16 c){
  return __builtin_amdgcn_mfma_f32_32x32x16_bf16(a, b, c, 0, 0, 0);
}
__device__ inline void stu(short* p, unsigned v){
  __hip_atomic_store((unsigned*)p, v, __ATOMIC_RELAXED, __HIP_MEMORY_SCOPE_AGENT);
}
__device__ inline void st8f(float* p, float a, float b){
  unsigned ua, ub; __builtin_memcpy(&ua, &a, 4); __builtin_memcpy(&ub, &b, 4);
  unsigned long long v = (unsigned long long)ua | ((unsigned long long)ub << 32);
  __hip_atomic_store((unsigned long long*)p, v, __ATOMIC_RELAXED, __HIP_MEMORY_SCOPE_AGENT);
}
__device__ inline unsigned pollld(const unsigned* p){
  return __hip_atomic_load(p, __ATOMIC_RELAXED, __HIP_MEMORY_SCOPE_AGENT);
}
__device__ inline short8 ldh8(const short* p){
  unsigned long long a = __hip_atomic_load((const unsigned long long*)p,
                          __ATOMIC_RELAXED, __HIP_MEMORY_SCOPE_AGENT);
  unsigned long long b = __hip_atomic_load((const unsigned long long*)(p+4),
                          __ATOMIC_RELAXED, __HIP_MEMORY_SCOPE_AGENT);
  short8 r;
  __builtin_memcpy(&r, &a, 8);
  __builtin_memcpy(((char*)&r)+8, &b, 8);
  return r;
}

// one poll of this lane's window flag -> 64-bit readiness ballot
__device__ inline unsigned long long pollbal(const unsigned* fp, unsigned e){
  unsigned f = pollld(fp);
  return __ballot(f >= e);
}

// ring-fallback: all 256 per-wave flags of a domain >= e
__device__ inline void waitflags_all256(const unsigned* f, unsigned e, int lane){
  for(;;){
    unsigned m0 = pollld(f + lane),       m1 = pollld(f + 64 + lane);
    unsigned m2 = pollld(f + 128 + lane), m3 = pollld(f + 192 + lane);
    if (__all((m0>=e) && (m1>=e) && (m2>=e) && (m3>=e))) break;
  }
  asm volatile("" ::: "memory");
}

// A-panel GEMM: K=256 eighth, 16 kg-pairs, dual accumulator chains (xf path).
__device__ inline void gemmA_core(const short* __restrict__ slot, int lane, int kgbase,
                                  const short8 (&bf)[2][16], f32x16& A0, f32x16& A1)
{
  const int row = lane & 31, ksel = lane >> 5;
  f32x16 x0, x1, y0, y1;
#pragma unroll
  for (int i = 0; i < 16; ++i){ x0[i]=0.f; x1[i]=0.f; y0[i]=0.f; y1[i]=0.f; }
#pragma unroll
  for (int s = 0; s < 16; s += 2){
    const short8 a  = *(const short8*)(slot + ((size_t)(kgbase + s*2     + ksel)*32 + row)*8);
    const short8 a2 = *(const short8*)(slot + ((size_t)(kgbase + (s+1)*2 + ksel)*32 + row)*8);
    x0 = MFMA(a,  bf[0][s],   x0);
    x1 = MFMA(a,  bf[1][s],   x1);
    y0 = MFMA(a2, bf[0][s+1], y0);
    y1 = MFMA(a2, bf[1][s+1], y1);
  }
  A0 = x0 + y0;
  A1 = x1 + y1;
}

// chunked opportunistic wait+GEMM: window = 64 flags (16 producers x 4 waves);
// chunk c = producers 4c..4c+3 <-> ballot bits 16c..16c+15. One initial poll;
// re-poll only for chunks not yet ready (overlaps earlier chunks' MFMA).
__device__ inline void gemmA_wait(const short* __restrict__ slot,
                                  const unsigned* __restrict__ win, unsigned e,
                                  int lane, int kgbase,
                                  const short8 (&bf)[2][16], f32x16& A0, f32x16& A1)
{
  const int row = lane & 31, ksel = lane >> 5;
  const unsigned* fp = win + lane;
  f32x16 x0, x1, y0, y1;
#pragma unroll
  for (int i = 0; i < 16; ++i){ x0[i]=0.f; x1[i]=0.f; y0[i]=0.f; y1[i]=0.f; }
  unsigned long long bal = pollbal(fp, e);
#pragma unroll
  for (int c = 0; c < 4; ++c){
    const unsigned long long m = 0xFFFFull << (c*16);
    while ((bal & m) != m) bal |= pollbal(fp, e);
    asm volatile("" ::: "memory");   // loads below must not hoist above the check
    const int s0 = 4*c;
    const short8 a0_ = *(const short8*)(slot + ((size_t)(kgbase + (s0  )*2 + ksel)*32 + row)*8);
    const short8 a1_ = *(const short8*)(slot + ((size_t)(kgbase + (s0+1)*2 + ksel)*32 + row)*8);
    const short8 a2_ = *(const short8*)(slot + ((size_t)(kgbase + (s0+2)*2 + ksel)*32 + row)*8);
    const short8 a3_ = *(const short8*)(slot + ((size_t)(kgbase + (s0+3)*2 + ksel)*32 + row)*8);
    x0 = MFMA(a0_, bf[0][s0  ], x0);
    x1 = MFMA(a0_, bf[1][s0  ], x1);
    y0 = MFMA(a1_, bf[0][s0+1], y0);
    y1 = MFMA(a1_, bf[1][s0+1], y1);
    x0 = MFMA(a2_, bf[0][s0+2], x0);
    x1 = MFMA(a2_, bf[1][s0+2], x1);
    y0 = MFMA(a3_, bf[0][s0+3], y0);
    y1 = MFMA(a3_, bf[1][s0+3], y1);
  }
  A0 = x0 + y0;
  A1 = x1 + y1;
}
__device__ inline void gemmA_bp(const short* __restrict__ slot, int lane, int kgbase,
                                const short8 (&bf)[2][16], f32x16& A0, f32x16& A1)
{
  const int row = lane & 31, ksel = lane >> 5;
  f32x16 x0, x1;
#pragma unroll
  for (int i = 0; i < 16; ++i){ x0[i]=0.f; x1[i]=0.f; }
#pragma unroll
  for (int s = 0; s < 16; ++s){
    const short8 a = ldh8(slot + ((size_t)(kgbase + s*2 + ksel)*32 + row)*8);
    x0 = MFMA(a, bf[0][s], x0);
    x1 = MFMA(a, bf[1][s], x1);
  }
  A0 = x0; A1 = x1;
}

// ---------------- prologue kernels ----------------

__global__ void lstm_prep(const float* __restrict__ bi, const float* __restrict__ bh,
                          float* __restrict__ bsum, unsigned* __restrict__ flags)
{
  int i = blockIdx.x*256 + threadIdx.x;
  if (i < 1024) flags[i] = 0;            // 4 domains x 64 blk x 4 pw-waves
  if (i < 2*NG) bsum[i] = bi[i] + bh[i];
}

// W_i/W_h [2][1024][4096] f32 -> wT [2][4096][2048] bf16 (gate-col major, k inner)
__global__ void lstm_tr(const float* __restrict__ Wi, const float* __restrict__ Wh,
                        short* __restrict__ wT)
{
  __shared__ float tile[32][33];
  const int z = blockIdx.z, l = z >> 1, s = z & 1;
  const float* W = (s ? Wh : Wi) + (size_t)l*1024*4096;
  const int k0 = blockIdx.y*32, n0 = blockIdx.x*32;
  const int tx = threadIdx.x & 31, ty = threadIdx.x >> 5;
#pragma unroll
  for (int i = 0; i < 32; i += 8)
    tile[ty+i][tx] = W[(size_t)(k0+ty+i)*4096 + n0 + tx];
  __syncthreads();
#pragma unroll
  for (int i = 0; i < 32; i += 8)
    wT[((size_t)l*NG + n0+ty+i)*KTOT + s*1024 + k0 + tx] = bfo(tile[tx][ty+i]);
}

// x [64][512][1024] f32 -> xf [512][2 rh][128 kg][32 r][8] bf16
__global__ void lstm_xfrag(const float* __restrict__ x, short* __restrict__ xf)
{
  const int t = blockIdx.x;
  const int rh = blockIdx.y >> 4, kgb = blockIdx.y & 15;   // grid (512, 32)
  const int r = threadIdx.x >> 3, kq = threadIdx.x & 7;
  const int kg = kgb*8 + kq;
  const int grow = rh*32 + r;
  const float* p = x + ((size_t)grow*SEQ + t)*HID + kg*8;
  float4 a = *(const float4*)p, b = *(const float4*)(p + 4);
  *(short8*)(xf + ((size_t)t*2 + rh)*SLOT32 + ((size_t)kg*32 + r)*8) = cvt8(a, b);
}

// ---------------- main persistent kernel ----------------

__global__ void __launch_bounds__(512, 1)
lstm_main(const float* __restrict__ x,
          const float* __restrict__ h0in,
          const float* __restrict__ c0in,
          float* __restrict__ dout,
          const short* __restrict__ wT,
          const float* __restrict__ bsum,
          short* __restrict__ hseq0,
          short* __restrict__ h1seq,
          unsigned* __restrict__ flags,
          const short* __restrict__ xf,
          int use_xf, int use_seq1)
{
  const int blk  = blockIdx.x;          // 256 blocks
  const int l    = blk & 1;             // layer
  const int rh   = (blk >> 1) & 1;      // row half (rows rh*32..+32)
  const int lblk = blk >> 2;            // 0..63, owns dims [lblk*16,+16)
  const int dom  = blk & 3;             // sync domain = (rh,l)
  const int dom0 = 2*rh;                // layer-0 domain of same row half
  const int tid  = threadIdx.x;
  const int lane = tid & 63;
  const int w    = tid >> 6;            // K-eighth: w<4 = x-part, w>=4 = h-part
  const int c31  = lane & 31;

  __shared__ float planes[8][32][65];   // one plane per wave
  __shared__ float cst[32][17];
  __shared__ float bsm[64];

  __builtin_amdgcn_fence(__ATOMIC_ACQUIRE, "agent");   // once: drop stale lines

  unsigned* dfl  = flags + dom*256;     // [64 blk][4 pw-wave] flags
  unsigned* dfl0 = flags + dom0*256;

  // pointwise mapping (waves 0-3): row = lane&31, dim pair dp = w*2 + (lane>>5)
  const int prow = lane & 31;
  const int pd0  = (w*2 + (lane>>5)) * 2;    // first of 2 dims (valid for w<4)

  // ---- init ----
  if (tid < 64) bsm[tid] = bsum[l*NG + (tid>>4)*HID + lblk*DPB + (tid&15)];
  if (w < 4){
    size_t o = ((size_t)l*B64 + rh*32 + prow)*HID + lblk*DPB + pd0;
    cst[prow][pd0]   = c0in[o];
    cst[prow][pd0+1] = c0in[o+1];
    const int kg = lblk*2 + (pd0>>3);
    short* hm1 = (l ? h1seq : hseq0) + (size_t)rh*SLOT32;   // slot 0 (both modes)
    stu(hm1 + ((size_t)kg*32 + prow)*8 + (pd0&7), packbf2(h0in[o], h0in[o+1]));
  }
  // persistent B fragments: 64 cols x 256 k = 128 VGPRs
  short8 bf[2][16];
  {
    const short* wl = wT + (size_t)l*NG*KTOT;
#pragma unroll
    for (int cI = 0; cI < 2; ++cI){
      const int c  = cI*32 + c31;
      const int gc = (c>>4)*HID + lblk*DPB + (c&15);
      const short* wp = wl + (size_t)gc*KTOT + w*256 + (lane>>5)*8;
#pragma unroll
      for (int s = 0; s < 16; ++s)
        bf[cI][s] = *(const short8*)(wp + s*16);
    }
  }
  __syncthreads();    // drains vmcnt: init write-through stores in LLC
  if (w < 4 && lane == 0)
    __hip_atomic_store(dfl + lblk*4 + w, 1u, __ATOMIC_RELAXED, __HIP_MEMORY_SCOPE_AGENT);

  float hf0 = 0.f, hf1 = 0.f;

  for (int t = 0; t < SEQ; ++t){
    f32x16 a0, a1;

    if (w < 4){
      // ---- x-part ----
      if (l == 0){
        if (use_xf){
          gemmA_core(xf + ((size_t)t*2 + rh)*SLOT32, lane, w*32, bf, a0, a1);
        } else {
          const int row = lane & 31, ksel = lane >> 5;
          const float* p = x + ((size_t)(rh*32 + row)*SEQ + t)*HID;
          f32x16 x0, x1;
#pragma unroll
          for (int i = 0; i < 16; ++i){ x0[i]=0.f; x1[i]=0.f; }
#pragma unroll
          for (int s = 0; s < 16; ++s){
            const int kg = w*32 + s*2 + ksel;
            short8 a = cvt8(*(const float4*)(p + kg*8), *(const float4*)(p + kg*8 + 4));
            x0 = MFMA(a, bf[0][s], x0);
            x1 = MFMA(a, bf[1][s], x1);
          }
          a0 = x0; a1 = x1;
        }
      } else {
        // layer-1 input = h0(t): hseq0 slot t+1; window = 16 l0 blocks x 4 waves
        gemmA_wait(hseq0 + ((size_t)(t+1)*2 + rh)*SLOT32,
                   dfl0 + w*64, (unsigned)t + 2u,
                   lane, w*32, bf, a0, a1);
      }
    } else {
      // ---- h-part: own layer h(t-1) ----
      if (l == 0){
        gemmA_wait(hseq0 + ((size_t)t*2 + rh)*SLOT32,
                   dfl + (w-4)*64, (unsigned)t + 1u,
                   lane, (w-4)*32, bf, a0, a1);
      } else if (use_seq1){
        gemmA_wait(h1seq + ((size_t)t*2 + rh)*SLOT32,
                   dfl + (w-4)*64, (unsigned)t + 1u,
                   lane, (w-4)*32, bf, a0, a1);
      } else {
        waitflags_all256(dfl, (unsigned)t + 1u, lane);
        gemmA_bp(h1seq + ((size_t)(t&1)*2 + rh)*SLOT32, lane, (w-4)*32, bf, a0, a1);
      }
    }

    // ---- each wave writes its OWN plane ----
#pragma unroll
    for (int r = 0; r < 16; ++r){
      const int rr = (r&3) + 8*(r>>2) + 4*(lane>>5);
      planes[w][rr][c31]      = a0[r];
      planes[w][rr][32 + c31] = a1[r];
    }
    __syncthreads();   // B2: all planes written

    // ---- pointwise (waves 0-3, all 64 lanes; 2 dims x 1 row each) ----
    if (w < 4){
      float hn[2];
#pragma unroll
      for (int e = 0; e < 2; ++e){
        const int d = pd0 + e;
        float gv[4];
#pragma unroll
        for (int g = 0; g < 4; ++g){
          float s = bsm[g*16 + d];
#pragma unroll
          for (int p = 0; p < 8; ++p)
            s += planes[p][prow][g*16 + d];
          gv[g] = s;
        }
        float cp = cst[prow][d];
        float cn = sigf(gv[1])*cp + sigf(gv[0])*tanhf2(gv[2]);
        float hv = sigf(gv[3])*tanhf2(cn);
        cst[prow][d] = cn;
        hn[e] = hv;
      }
      hf0 = hn[0]; hf1 = hn[1];
      const int kg = lblk*2 + (pd0>>3);
      short* so;
      if (l == 0)           so = hseq0 + ((size_t)(t+1)*2 + rh)*SLOT32;
      else if (use_seq1)    so = h1seq + ((size_t)(t+1)*2 + rh)*SLOT32;
      else                  so = h1seq + ((size_t)((t+1)&1)*2 + rh)*SLOT32;
      stu(so + ((size_t)kg*32 + prow)*8 + (pd0&7), packbf2(hn[0], hn[1]));
      asm volatile("s_waitcnt vmcnt(0)" ::: "memory");   // wave-local store ack
      if (lane == 0)
        __hip_atomic_store(dfl + lblk*4 + w, (unsigned)t + 2u,
                           __ATOMIC_RELAXED, __HIP_MEMORY_SCOPE_AGENT);
      // off critical path: layer-1 output write
      if (l == 1)
        st8f(dout + ((size_t)(rh*32 + prow)*SEQ + t)*HID + lblk*DPB + pd0, hn[0], hn[1]);
    }
    __syncthreads();   // B3: planes/cst reusable next step
  }

  // ---- epilogue: h_n / c_n ----
  if (w < 4){
    const int grow = rh*32 + prow;
    const size_t tb = (size_t)B64*SEQ*HID;
    size_t o = ((size_t)l*B64 + grow)*HID + lblk*DPB + pd0;
    st8f(dout + tb + o, hf0, hf1);
    st8f(dout + tb + (size_t)2*B64*HID + o, cst[prow][pd0], cst[prow][pd0+1]);
  }
}

// ---------------- host ----------------

extern "C" void kernel_launch(void* const* d_in, const int* in_sizes, int n_in,
                              void* d_out, int out_size, void* d_ws, size_t ws_size,
                              hipStream_t stream)
{
  const float* x  = (const float*)d_in[0];
  const float* Wi = (const float*)d_in[1];
  const float* bi = (const float*)d_in[2];
  const float* Wh = (const float*)d_in[3];
  const float* bh = (const float*)d_in[4];
  const float* h0 = (const float*)d_in[5];
  const float* c0 = (const float*)d_in[6];
  float* out = (float*)d_out;

  char* ws = (char*)d_ws;
  unsigned* flags = (unsigned*)ws;                     // 4 dom x 64 blk x 4 w
  float*    bsum  = (float*)(ws + 16384);              // 32 KB
  short*    wT    = (short*)(ws + 131072);             // 32 MB

  const size_t wT_bytes  = (size_t)2*NG*KTOT*2;        // 33,554,432
  const size_t seq_bytes = (size_t)NSLOT*2*SLOT32*2;   // 67.2 MB
  size_t off = 131072 + wT_bytes;

  short* hseq0 = (short*)(ws + off); off += seq_bytes; // required
  if (ws_size < off) return;

  int use_seq1 = 0;
  short* h1seq = (short*)(ws + off);
  if (ws_size >= off + seq_bytes){ use_seq1 = 1; off += seq_bytes; }
  else {
    if (ws_size < off + (size_t)2*2*SLOT32*2) return;  // 2-slot ring, 256 KB
    off += (size_t)2*2*SLOT32*2;
  }

  int use_xf = 0;
  short* xf = (short*)(ws + off);
  if (ws_size >= off + (size_t)SEQ*2*SLOT32*2) use_xf = 1;   // +67 MB

  lstm_prep<<<32, 256, 0, stream>>>(bi, bh, bsum, flags);
  lstm_tr<<<dim3(128, 32, 4), 256, 0, stream>>>(Wi, Wh, wT);
  if (use_xf) lstm_xfrag<<<dim3(SEQ, 32), 256, 0, stream>>>(x, xf);
  lstm_main<<<256, 512, 0, stream>>>(x, h0, c0, out, wT, bsum, hseq0, h1seq,
                                     flags, xf, use_xf, use_seq1);
}

// Round 13
// 3162.309 us; speedup vs baseline: 1.3767x; 1.3015x over previous
//
#include <hip/hip_runtime.h>
#include <hip/hip_bf16.h>

// LSTM B=64 L=512 H=1024 x2, persistent kernel v13 == v8 (measured best: 3.16ms).
// v9 (full-line remap), v10 (sentinel), v11 (no-B3), v12 (chunked wait) each
// tested one lever of this structure and ALL regressed -- reverted here.
// Structure: 256 blocks = 2 layers x 2 row-halves x 64 col-blocks; 4 sync
// domains; W dup x2 in VGPRs (128/wave); per-pw-wave flags posted after
// wave-local vmcnt(0); pipelined 2-outstanding flag poll; slot-per-t h buffers
// (plain cached consumer loads, write-through producer stores); B2+B3 lockstep.

#define B64  64
#define SEQ  512
#define HID  1024
#define KTOT 2048
#define NG   4096
#define DPB  16
#define SLOT32 32768           // shorts per (t, rhalf) frag slot = 128kg*32r*8
#define NSLOT (SEQ+1)

typedef __attribute__((ext_vector_type(8)))  short short8;
typedef __attribute__((ext_vector_type(16))) float f32x16;

__device__ inline short bfo(float v){
  __hip_bfloat16 h = __float2bfloat16(v);
  short s; __builtin_memcpy(&s, &h, 2); return s;
}
__device__ inline unsigned packbf2(float a, float b){
  return (unsigned)(unsigned short)bfo(a) | ((unsigned)(unsigned short)bfo(b) << 16);
}
__device__ inline short8 cvt8(float4 a, float4 b){
  short8 r;
  r[0]=bfo(a.x); r[1]=bfo(a.y); r[2]=bfo(a.z); r[3]=bfo(a.w);
  r[4]=bfo(b.x); r[5]=bfo(b.y); r[6]=bfo(b.z); r[7]=bfo(b.w);
  return r;
}
__device__ inline float frcp(float x){ float r; asm("v_rcp_f32 %0, %1" : "=v"(r) : "v"(x)); return r; }
__device__ inline float sigf(float v){ return frcp(1.f + __expf(-v)); }
__device__ inline float tanhf2(float v){
  float a = fabsf(v);
  float e = __expf(-2.f*a);
  float r = (1.f - e) * frcp(1.f + e);
  return v < 0.f ? -r : r;
}
__device__ inline f32x16 MFMA(short8 a, short8 b, f32x16 c){
  return __builtin_amdgcn_mfma_f32_32x32x16_bf16(a, b, c, 0, 0, 0);
}
__device__ inline void stu(short* p, unsigned v){
  __hip_atomic_store((unsigned*)p, v, __ATOMIC_RELAXED, __HIP_MEMORY_SCOPE_AGENT);
}
__device__ inline void st8f(float* p, float a, float b){
  unsigned ua, ub; __builtin_memcpy(&ua, &a, 4); __builtin_memcpy(&ub, &b, 4);
  unsigned long long v = (unsigned long long)ua | ((unsigned long long)ub << 32);
  __hip_atomic_store((unsigned long long*)p, v, __ATOMIC_RELAXED, __HIP_MEMORY_SCOPE_AGENT);
}
__device__ inline unsigned pollld(const unsigned* p){
  return __hip_atomic_load(p, __ATOMIC_RELAXED, __HIP_MEMORY_SCOPE_AGENT);
}
__device__ inline short8 ldh8(const short* p){
  unsigned long long a = __hip_atomic_load((const unsigned long long*)p,
                          __ATOMIC_RELAXED, __HIP_MEMORY_SCOPE_AGENT);
  unsigned long long b = __hip_atomic_load((const unsigned long long*)(p+4),
                          __ATOMIC_RELAXED, __HIP_MEMORY_SCOPE_AGENT);
  short8 r;
  __builtin_memcpy(&r, &a, 8);
  __builtin_memcpy(((char*)&r)+8, &b, 8);
  return r;
}

// pipelined 2-outstanding poll: lane checks win[lane] >= e, all 64 lanes.
__device__ inline void wait_ge(const unsigned* win, unsigned e, int lane){
  const unsigned* fp = win + lane;
  unsigned f0, f1;
  asm volatile(
    "global_load_dword %[f0], %[ad], off sc0 sc1\n\t"
    "Lp%=:\n\t"
    "global_load_dword %[f1], %[ad], off sc0 sc1\n\t"
    "s_waitcnt vmcnt(1)\n\t"
    "v_cmp_ge_u32 vcc, %[f0], %[e]\n\t"
    "s_cmp_eq_u64 vcc, -1\n\t"
    "s_cbranch_scc1 Ld%=\n\t"
    "global_load_dword %[f0], %[ad], off sc0 sc1\n\t"
    "s_waitcnt vmcnt(1)\n\t"
    "v_cmp_ge_u32 vcc, %[f1], %[e]\n\t"
    "s_cmp_eq_u64 vcc, -1\n\t"
    "s_cbranch_scc0 Lp%=\n\t"
    "Ld%=:\n\t"
    "s_waitcnt vmcnt(0)\n\t"
    : [f0]"=&v"(f0), [f1]"=&v"(f1)
    : [ad]"v"(fp), [e]"v"(e)
    : "vcc", "scc", "memory");
}

// ring-fallback: all 256 per-wave flags of a domain >= e
__device__ inline void waitflags_all256(const unsigned* f, unsigned e, int lane){
  for(;;){
    unsigned m0 = pollld(f + lane),       m1 = pollld(f + 64 + lane);
    unsigned m2 = pollld(f + 128 + lane), m3 = pollld(f + 192 + lane);
    if (__all((m0>=e) && (m1>=e) && (m2>=e) && (m3>=e))) break;
  }
  asm volatile("" ::: "memory");
}

// A-panel GEMM: K=256 eighth, 16 kg-pairs, dual accumulator chains.
__device__ inline void gemmA_core(const short* __restrict__ slot, int lane, int kgbase,
                                  const short8 (&bf)[2][16], f32x16& A0, f32x16& A1)
{
  const int row = lane & 31, ksel = lane >> 5;
  f32x16 x0, x1, y0, y1;
#pragma unroll
  for (int i = 0; i < 16; ++i){ x0[i]=0.f; x1[i]=0.f; y0[i]=0.f; y1[i]=0.f; }
#pragma unroll
  for (int s = 0; s < 16; s += 2){
    const short8 a  = *(const short8*)(slot + ((size_t)(kgbase + s*2     + ksel)*32 + row)*8);
    const short8 a2 = *(const short8*)(slot + ((size_t)(kgbase + (s+1)*2 + ksel)*32 + row)*8);
    x0 = MFMA(a,  bf[0][s],   x0);
    x1 = MFMA(a,  bf[1][s],   x1);
    y0 = MFMA(a2, bf[0][s+1], y0);
    y1 = MFMA(a2, bf[1][s+1], y1);
  }
  A0 = x0 + y0;
  A1 = x1 + y1;
}
__device__ inline void gemmA_wait(const short* __restrict__ slot,
                                  const unsigned* __restrict__ win, unsigned e,
                                  int lane, int kgbase,
                                  const short8 (&bf)[2][16], f32x16& A0, f32x16& A1)
{
  wait_ge(win, e, lane);
  gemmA_core(slot, lane, kgbase, bf, A0, A1);
}
__device__ inline void gemmA_bp(const short* __restrict__ slot, int lane, int kgbase,
                                const short8 (&bf)[2][16], f32x16& A0, f32x16& A1)
{
  const int row = lane & 31, ksel = lane >> 5;
  f32x16 x0, x1;
#pragma unroll
  for (int i = 0; i < 16; ++i){ x0[i]=0.f; x1[i]=0.f; }
#pragma unroll
  for (int s = 0; s < 16; ++s){
    const short8 a = ldh8(slot + ((size_t)(kgbase + s*2 + ksel)*32 + row)*8);
    x0 = MFMA(a, bf[0][s], x0);
    x1 = MFMA(a, bf[1][s], x1);
  }
  A0 = x0; A1 = x1;
}

// ---------------- prologue kernels ----------------

__global__ void lstm_prep(const float* __restrict__ bi, const float* __restrict__ bh,
                          float* __restrict__ bsum, unsigned* __restrict__ flags)
{
  int i = blockIdx.x*256 + threadIdx.x;
  if (i < 1024) flags[i] = 0;            // 4 domains x 64 blk x 4 pw-waves
  if (i < 2*NG) bsum[i] = bi[i] + bh[i];
}

// W_i/W_h [2][1024][4096] f32 -> wT [2][4096][2048] bf16 (gate-col major, k inner)
__global__ void lstm_tr(const float* __restrict__ Wi, const float* __restrict__ Wh,
                        short* __restrict__ wT)
{
  __shared__ float tile[32][33];
  const int z = blockIdx.z, l = z >> 1, s = z & 1;
  const float* W = (s ? Wh : Wi) + (size_t)l*1024*4096;
  const int k0 = blockIdx.y*32, n0 = blockIdx.x*32;
  const int tx = threadIdx.x & 31, ty = threadIdx.x >> 5;
#pragma unroll
  for (int i = 0; i < 32; i += 8)
    tile[ty+i][tx] = W[(size_t)(k0+ty+i)*4096 + n0 + tx];
  __syncthreads();
#pragma unroll
  for (int i = 0; i < 32; i += 8)
    wT[((size_t)l*NG + n0+ty+i)*KTOT + s*1024 + k0 + tx] = bfo(tile[tx][ty+i]);
}

// x [64][512][1024] f32 -> xf [512][2 rh][128 kg][32 r][8] bf16
__global__ void lstm_xfrag(const float* __restrict__ x, short* __restrict__ xf)
{
  const int t = blockIdx.x;
  const int rh = blockIdx.y >> 4, kgb = blockIdx.y & 15;   // grid (512, 32)
  const int r = threadIdx.x >> 3, kq = threadIdx.x & 7;
  const int kg = kgb*8 + kq;
  const int grow = rh*32 + r;
  const float* p = x + ((size_t)grow*SEQ + t)*HID + kg*8;
  float4 a = *(const float4*)p, b = *(const float4*)(p + 4);
  *(short8*)(xf + ((size_t)t*2 + rh)*SLOT32 + ((size_t)kg*32 + r)*8) = cvt8(a, b);
}

// ---------------- main persistent kernel ----------------

__global__ void __launch_bounds__(512, 1)
lstm_main(const float* __restrict__ x,
          const float* __restrict__ h0in,
          const float* __restrict__ c0in,
          float* __restrict__ dout,
          const short* __restrict__ wT,
          const float* __restrict__ bsum,
          short* __restrict__ hseq0,
          short* __restrict__ h1seq,
          unsigned* __restrict__ flags,
          const short* __restrict__ xf,
          int use_xf, int use_seq1)
{
  const int blk  = blockIdx.x;          // 256 blocks
  const int l    = blk & 1;             // layer
  const int rh   = (blk >> 1) & 1;      // row half (rows rh*32..+32)
  const int lblk = blk >> 2;            // 0..63, owns dims [lblk*16,+16)
  const int dom  = blk & 3;             // sync domain = (rh,l)
  const int dom0 = 2*rh;                // layer-0 domain of same row half
  const int tid  = threadIdx.x;
  const int lane = tid & 63;
  const int w    = tid >> 6;            // K-eighth: w<4 = x-part, w>=4 = h-part
  const int c31  = lane & 31;

  __shared__ float planes[8][32][65];   // one plane per wave
  __shared__ float cst[32][17];
  __shared__ float bsm[64];

  __builtin_amdgcn_fence(__ATOMIC_ACQUIRE, "agent");   // once: drop stale lines

  unsigned* dfl  = flags + dom*256;     // [64 blk][4 pw-wave] flags
  unsigned* dfl0 = flags + dom0*256;

  // pointwise mapping (waves 0-3): row = lane&31, dim pair dp = w*2 + (lane>>5)
  const int prow = lane & 31;
  const int pd0  = (w*2 + (lane>>5)) * 2;    // first of 2 dims (valid for w<4)

  // ---- init ----
  if (tid < 64) bsm[tid] = bsum[l*NG + (tid>>4)*HID + lblk*DPB + (tid&15)];
  if (w < 4){
    size_t o = ((size_t)l*B64 + rh*32 + prow)*HID + lblk*DPB + pd0;
    cst[prow][pd0]   = c0in[o];
    cst[prow][pd0+1] = c0in[o+1];
    const int kg = lblk*2 + (pd0>>3);
    short* hm1 = (l ? h1seq : hseq0) + (size_t)rh*SLOT32;   // slot 0 (both modes)
    stu(hm1 + ((size_t)kg*32 + prow)*8 + (pd0&7), packbf2(h0in[o], h0in[o+1]));
  }
  // persistent B fragments: 64 cols x 256 k = 128 VGPRs
  short8 bf[2][16];
  {
    const short* wl = wT + (size_t)l*NG*KTOT;
#pragma unroll
    for (int cI = 0; cI < 2; ++cI){
      const int c  = cI*32 + c31;
      const int gc = (c>>4)*HID + lblk*DPB + (c&15);
      const short* wp = wl + (size_t)gc*KTOT + w*256 + (lane>>5)*8;
#pragma unroll
      for (int s = 0; s < 16; ++s)
        bf[cI][s] = *(const short8*)(wp + s*16);
    }
  }
  __syncthreads();    // drains vmcnt: init write-through stores in LLC
  if (w < 4 && lane == 0)
    __hip_atomic_store(dfl + lblk*4 + w, 1u, __ATOMIC_RELAXED, __HIP_MEMORY_SCOPE_AGENT);

  float hf0 = 0.f, hf1 = 0.f;

  for (int t = 0; t < SEQ; ++t){
    f32x16 a0, a1;

    if (w < 4){
      // ---- x-part ----
      if (l == 0){
        if (use_xf){
          gemmA_core(xf + ((size_t)t*2 + rh)*SLOT32, lane, w*32, bf, a0, a1);
        } else {
          const int row = lane & 31, ksel = lane >> 5;
          const float* p = x + ((size_t)(rh*32 + row)*SEQ + t)*HID;
          f32x16 x0, x1;
#pragma unroll
          for (int i = 0; i < 16; ++i){ x0[i]=0.f; x1[i]=0.f; }
#pragma unroll
          for (int s = 0; s < 16; ++s){
            const int kg = w*32 + s*2 + ksel;
            short8 a = cvt8(*(const float4*)(p + kg*8), *(const float4*)(p + kg*8 + 4));
            x0 = MFMA(a, bf[0][s], x0);
            x1 = MFMA(a, bf[1][s], x1);
          }
          a0 = x0; a1 = x1;
        }
      } else {
        // layer-1 input = h0(t): hseq0 slot t+1; window = 16 l0 blocks x 4 waves
        gemmA_wait(hseq0 + ((size_t)(t+1)*2 + rh)*SLOT32,
                   dfl0 + w*64, (unsigned)t + 2u,
                   lane, w*32, bf, a0, a1);
      }
    } else {
      // ---- h-part: own layer h(t-1) ----
      if (l == 0){
        gemmA_wait(hseq0 + ((size_t)t*2 + rh)*SLOT32,
                   dfl + (w-4)*64, (unsigned)t + 1u,
                   lane, (w-4)*32, bf, a0, a1);
      } else if (use_seq1){
        gemmA_wait(h1seq + ((size_t)t*2 + rh)*SLOT32,
                   dfl + (w-4)*64, (unsigned)t + 1u,
                   lane, (w-4)*32, bf, a0, a1);
      } else {
        waitflags_all256(dfl, (unsigned)t + 1u, lane);
        gemmA_bp(h1seq + ((size_t)(t&1)*2 + rh)*SLOT32, lane, (w-4)*32, bf, a0, a1);
      }
    }

    // ---- each wave writes its OWN plane ----
#pragma unroll
    for (int r = 0; r < 16; ++r){
      const int rr = (r&3) + 8*(r>>2) + 4*(lane>>5);
      planes[w][rr][c31]      = a0[r];
      planes[w][rr][32 + c31] = a1[r];
    }
    __syncthreads();   // B2: all planes written

    // ---- pointwise (waves 0-3, all 64 lanes; 2 dims x 1 row each) ----
    if (w < 4){
      float hn[2];
#pragma unroll
      for (int e = 0; e < 2; ++e){
        const int d = pd0 + e;
        float gv[4];
#pragma unroll
        for (int g = 0; g < 4; ++g){
          float s = bsm[g*16 + d];
#pragma unroll
          for (int p = 0; p < 8; ++p)
            s += planes[p][prow][g*16 + d];
          gv[g] = s;
        }
        float cp = cst[prow][d];
        float cn = sigf(gv[1])*cp + sigf(gv[0])*tanhf2(gv[2]);
        float hv = sigf(gv[3])*tanhf2(cn);
        cst[prow][d] = cn;
        hn[e] = hv;
      }
      hf0 = hn[0]; hf1 = hn[1];
      const int kg = lblk*2 + (pd0>>3);
      short* so;
      if (l == 0)           so = hseq0 + ((size_t)(t+1)*2 + rh)*SLOT32;
      else if (use_seq1)    so = h1seq + ((size_t)(t+1)*2 + rh)*SLOT32;
      else                  so = h1seq + ((size_t)((t+1)&1)*2 + rh)*SLOT32;
      stu(so + ((size_t)kg*32 + prow)*8 + (pd0&7), packbf2(hn[0], hn[1]));
      asm volatile("s_waitcnt vmcnt(0)" ::: "memory");   // wave-local store ack
      if (lane == 0)
        __hip_atomic_store(dfl + lblk*4 + w, (unsigned)t + 2u,
                           __ATOMIC_RELAXED, __HIP_MEMORY_SCOPE_AGENT);
      // off critical path: layer-1 output write
      if (l == 1)
        st8f(dout + ((size_t)(rh*32 + prow)*SEQ + t)*HID + lblk*DPB + pd0, hn[0], hn[1]);
    }
    __syncthreads();   // B3: planes/cst reusable next step
  }

  // ---- epilogue: h_n / c_n ----
  if (w < 4){
    const int grow = rh*32 + prow;
    const size_t tb = (size_t)B64*SEQ*HID;
    size_t o = ((size_t)l*B64 + grow)*HID + lblk*DPB + pd0;
    st8f(dout + tb + o, hf0, hf1);
    st8f(dout + tb + (size_t)2*B64*HID + o, cst[prow][pd0], cst[prow][pd0+1]);
  }
}

// ---------------- host ----------------

extern "C" void kernel_launch(void* const* d_in, const int* in_sizes, int n_in,
                              void* d_out, int out_size, void* d_ws, size_t ws_size,
                              hipStream_t stream)
{
  const float* x  = (const float*)d_in[0];
  const float* Wi = (const float*)d_in[1];
  const float* bi = (const float*)d_in[2];
  const float* Wh = (const float*)d_in[3];
  const float* bh = (const float*)d_in[4];
  const float* h0 = (const float*)d_in[5];
  const float* c0 = (const float*)d_in[6];
  float* out = (float*)d_out;

  char* ws = (char*)d_ws;
  unsigned* flags = (unsigned*)ws;                     // 4 dom x 64 blk x 4 w
  float*    bsum  = (float*)(ws + 16384);              // 32 KB
  short*    wT    = (short*)(ws + 131072);             // 32 MB

  const size_t wT_bytes  = (size_t)2*NG*KTOT*2;        // 33,554,432
  const size_t seq_bytes = (size_t)NSLOT*2*SLOT32*2;   // 67.2 MB
  size_t off = 131072 + wT_bytes;

  short* hseq0 = (short*)(ws + off); off += seq_bytes; // required
  if (ws_size < off) return;

  int use_seq1 = 0;
  short* h1seq = (short*)(ws + off);
  if (ws_size >= off + seq_bytes){ use_seq1 = 1; off += seq_bytes; }
  else {
    if (ws_size < off + (size_t)2*2*SLOT32*2) return;  // 2-slot ring, 256 KB
    off += (size_t)2*2*SLOT32*2;
  }

  int use_xf = 0;
  short* xf = (short*)(ws + off);
  if (ws_size >= off + (size_t)SEQ*2*SLOT32*2) use_xf = 1;   // +67 MB

  lstm_prep<<<32, 256, 0, stream>>>(bi, bh, bsum, flags);
  lstm_tr<<<dim3(128, 32, 4), 256, 0, stream>>>(Wi, Wh, wT);
  if (use_xf) lstm_xfrag<<<dim3(SEQ, 32), 256, 0, stream>>>(x, xf);
  lstm_main<<<256, 512, 0, stream>>>(x, h0, c0, out, wT, bsum, hseq0, h1seq,
                                     flags, xf, use_xf, use_seq1);
}